// Round 4
// baseline (1427.933 us; speedup 1.0000x reference)
//
#include <hip/hip_runtime.h>
#include <hip/hip_bf16.h>

// n=4, c=512, h=w=64. Runtime dtype via detect_f32 (R3-proven).
#define NBATCH 4
#define C 512
#define HW 4096
#define GROUPS 32
#define EPSV 1e-5f
// attention scale folded with 1/ln2 (softmax runs in exp2 domain):
// 1/sqrt(512) * log2(e)
#define ATTN_SCALE_L2 0.0637587085f

typedef short bf16x8 __attribute__((ext_vector_type(8)));  // 8 bf16 = 4 VGPR
typedef float f32x4 __attribute__((ext_vector_type(4)));

__device__ __forceinline__ float bf(unsigned short u) {
  return __uint_as_float(((unsigned)u) << 16);
}
__device__ __forceinline__ unsigned short fb(float v) {
  __hip_bfloat16 h = __float2bfloat16(v);
  return *(unsigned short*)&h;
}
__device__ __forceinline__ bf16x8 frag_ld(const short* p) {
  return *(const bf16x8*)p;  // 16B-aligned by construction
}
#define MFMA(a, b, c) __builtin_amdgcn_mfma_f32_16x16x32_bf16((a), (b), (c), 0, 0, 0)

#define SCHED_FENCE() __builtin_amdgcn_sched_barrier(0)
// raw barrier (NO vmcnt drain) + compiler/scheduler fences (rule #18 / m152)
#define BAR()                                   \
  do {                                          \
    asm volatile("" ::: "memory");              \
    SCHED_FENCE();                              \
    __builtin_amdgcn_s_barrier();               \
    SCHED_FENCE();                              \
    asm volatile("" ::: "memory");              \
  } while (0)
#define WAITV(N)                                                  \
  do {                                                            \
    asm volatile("s_waitcnt vmcnt(" #N ")" ::: "memory");         \
    SCHED_FENCE();                                                \
  } while (0)

// async global->LDS, 16B per lane; LDS dest is wave-uniform base + lane*16
__device__ __forceinline__ void gl_lds16(const short* g, short* l) {
  __builtin_amdgcn_global_load_lds(
      (const __attribute__((address_space(1))) unsigned int*)g,
      (__attribute__((address_space(3))) unsigned int*)l, 16, 0, 0);
}

__device__ __forceinline__ void unpack8(uint4 w, float* f) {
  f[0] = __uint_as_float(w.x << 16);
  f[1] = __uint_as_float(w.x & 0xFFFF0000u);
  f[2] = __uint_as_float(w.y << 16);
  f[3] = __uint_as_float(w.y & 0xFFFF0000u);
  f[4] = __uint_as_float(w.z << 16);
  f[5] = __uint_as_float(w.z & 0xFFFF0000u);
  f[6] = __uint_as_float(w.w << 16);
  f[7] = __uint_as_float(w.w & 0xFFFF0000u);
}

// Runtime dtype detection (R3-proven).
__device__ __forceinline__ bool detect_f32(const void* w_in) {
  const unsigned short* u = (const unsigned short*)w_in;
  bool f32 = false;
#pragma unroll
  for (int i = 0; i < 64; ++i) {
    float v = bf(u[i]);
    if (!(fabsf(v) < 1e3f)) f32 = true;  // NaN -> true
  }
  return f32;
}
__device__ __forceinline__ float ld(const void* p, size_t i, bool f32) {
  if (f32) return ((const float*)p)[i];
  return bf(((const unsigned short*)p)[i]);
}

// MFMA A-fragment (8 contiguous k-elements) from a weight matrix, either dtype.
__device__ __forceinline__ bf16x8 wfrag(const void* w, size_t off, bool f32) {
  if (f32) {
    const float4* p = (const float4*)((const float*)w + off);
    float4 w0 = p[0], w1 = p[1];
    bf16x8 r;
    r[0] = (short)fb(w0.x); r[1] = (short)fb(w0.y);
    r[2] = (short)fb(w0.z); r[3] = (short)fb(w0.w);
    r[4] = (short)fb(w1.x); r[5] = (short)fb(w1.y);
    r[6] = (short)fb(w1.z); r[7] = (short)fb(w1.w);
    return r;
  }
  return frag_ld((const short*)w + off);
}

// Stage GN-normalized x rows [t0, t0+32) into xn[32][520] (bf16). R3-proven.
__device__ __forceinline__ void stage_xn(short* xn, const void* x,
                                         const void* gsc, const void* gbi,
                                         const float* stats, int nn, int t0,
                                         bool f32) {
  const int tid = threadIdx.x;
  const int part = tid & 3, crel = tid >> 2;
  for (int c0 = 0; c0 < 512; c0 += 64) {
    int c = c0 + crel;
    float rr = stats[128 + nn * GROUPS + (c >> 4)];
    float mu = stats[nn * GROUPS + (c >> 4)];
    float scl = ld(gsc, c, f32) * rr;
    float sft = ld(gbi, c, f32) - mu * scl;
    float f[8];
    if (f32) {
      const float4* p = (const float4*)((const float*)x +
                                        ((size_t)(nn * C + c) << 12) + t0 + part * 8);
      float4 r0 = p[0], r1 = p[1];
      f[0] = r0.x; f[1] = r0.y; f[2] = r0.z; f[3] = r0.w;
      f[4] = r1.x; f[5] = r1.y; f[6] = r1.z; f[7] = r1.w;
    } else {
      uint4 raw = *(const uint4*)((const unsigned short*)x +
                                  ((size_t)(nn * C + c) << 12) + t0 + part * 8);
      unpack8(raw, f);
    }
#pragma unroll
    for (int j = 0; j < 8; ++j)
      xn[(part * 8 + j) * 520 + c] = (short)fb(f[j] * scl + sft);
  }
}

// 16-row variant for the flash Q-phase (LDS-slim).
__device__ __forceinline__ void stage_xn16(short* xn, const void* x,
                                           const void* gsc, const void* gbi,
                                           const float* stats, int nn, int t0,
                                           bool f32) {
  const int tid = threadIdx.x;
  const int part = tid & 1, crel = tid >> 1;  // 2 x 8 rows, 128 c-lanes
  for (int c0 = 0; c0 < 512; c0 += 128) {
    int c = c0 + crel;
    float rr = stats[128 + nn * GROUPS + (c >> 4)];
    float mu = stats[nn * GROUPS + (c >> 4)];
    float scl = ld(gsc, c, f32) * rr;
    float sft = ld(gbi, c, f32) - mu * scl;
    float f[8];
    if (f32) {
      const float4* p = (const float4*)((const float*)x +
                                        ((size_t)(nn * C + c) << 12) + t0 + part * 8);
      float4 r0 = p[0], r1 = p[1];
      f[0] = r0.x; f[1] = r0.y; f[2] = r0.z; f[3] = r0.w;
      f[4] = r1.x; f[5] = r1.y; f[6] = r1.z; f[7] = r1.w;
    } else {
      uint4 raw = *(const uint4*)((const unsigned short*)x +
                                  ((size_t)(nn * C + c) << 12) + t0 + part * 8);
      unpack8(raw, f);
    }
#pragma unroll
    for (int j = 0; j < 8; ++j)
      xn[(part * 8 + j) * 520 + c] = (short)fb(f[j] * scl + sft);
  }
}

// ---------------------------------------------------------------------------
// GroupNorm stats — R3-proven verbatim.
// ---------------------------------------------------------------------------
__global__ __launch_bounds__(256) void gn_stats_kernel(
    const void* __restrict__ x, const void* __restrict__ w_in,
    float* __restrict__ stats) {
  const bool f32 = detect_f32(w_in);
  const int b = blockIdx.x;
  const size_t base = (size_t)b << 16;
  float s = 0.f, ss = 0.f;
  for (int i = threadIdx.x; i < 65536; i += 256) {
    float v = ld(x, base + i, f32);
    s += v;
    ss += v * v;
  }
  __shared__ float rs[256], rq[256];
  rs[threadIdx.x] = s;
  rq[threadIdx.x] = ss;
  __syncthreads();
  for (int off = 128; off > 0; off >>= 1) {
    if (threadIdx.x < off) {
      rs[threadIdx.x] += rs[threadIdx.x + off];
      rq[threadIdx.x] += rq[threadIdx.x + off];
    }
    __syncthreads();
  }
  if (threadIdx.x == 0) {
    float m = rs[0] * (1.0f / 65536.0f);
    float var = rq[0] * (1.0f / 65536.0f) - m * m;
    stats[b] = m;
    stats[128 + b] = rsqrtf(var + EPSV);
  }
}

// ---------------------------------------------------------------------------
// kv_gemm — proven MFMA core. Epilogue writes:
//   K: kbuf[t][col] PRE-SWIZZLED: granule g=e>>3 stored at g^(t&7)
//      (flash global_load_lds linear, ds_read_b128 conflict-free).
//   V: vbuf tiled [tk][e][t&31] PLAIN (V is now read direct from L2 by the
//      flash PV as contiguous 1KB coalesced loads — no LDS, no swizzle).
// ---------------------------------------------------------------------------
__global__ __launch_bounds__(256) void kv_gemm_kernel(
    const void* __restrict__ x, const void* __restrict__ gsc,
    const void* __restrict__ gbi, const float* __restrict__ stats,
    const void* __restrict__ w_in, const void* __restrict__ b_in,
    unsigned short* __restrict__ kvbase, int nn0) {
  const bool f32 = detect_f32(w_in);
  const int nn = nn0 + blockIdx.z;
  unsigned short* kbuf = kvbase + (size_t)blockIdx.z * 4194304;
  unsigned short* vbuf = kbuf + 2097152;
  __shared__ __align__(16) short xn[32 * 520];
  const int tid = threadIdx.x;
  const int wave = tid >> 6, lane = tid & 63, l15 = lane & 15, quad = lane >> 4;
  const int t0 = blockIdx.y * 32;
  const int proj = blockIdx.x >> 1;  // 0 = K, 1 = V
  const int ehalf = blockIdx.x & 1;

  stage_xn(xn, x, gsc, gbi, stats, nn, t0, f32);
  __syncthreads();

  const int wrow = 512 + proj * 512 + ehalf * 256 + wave * 64;  // w_in row
  const int cbase = ehalf * 256 + wave * 64;                    // col in [0,512)

  f32x4 acc[4][2];
#pragma unroll
  for (int i = 0; i < 4; ++i) {
    acc[i][0] = {0.f, 0.f, 0.f, 0.f};
    acc[i][1] = {0.f, 0.f, 0.f, 0.f};
  }

  for (int kc = 0; kc < 16; ++kc) {
    bf16x8 b0f = frag_ld(xn + l15 * 520 + kc * 32 + quad * 8);
    bf16x8 b1f = frag_ld(xn + (16 + l15) * 520 + kc * 32 + quad * 8);
#pragma unroll
    for (int es = 0; es < 4; ++es) {
      bf16x8 a = wfrag(w_in, (size_t)(wrow + es * 16 + l15) * 512 + kc * 32 + quad * 8, f32);
      acc[es][0] = MFMA(a, b0f, acc[es][0]);
      acc[es][1] = MFMA(a, b1f, acc[es][1]);
    }
  }

#pragma unroll
  for (int es = 0; es < 4; ++es) {
    int bidx = wrow + es * 16 + quad * 4;
    float b0 = ld(b_in, bidx, f32), b1 = ld(b_in, bidx + 1, f32);
    float b2 = ld(b_in, bidx + 2, f32), b3 = ld(b_in, bidx + 3, f32);
    int ecol = cbase + es * 16 + quad * 4;
#pragma unroll
    for (int ts = 0; ts < 2; ++ts) {
      int t = t0 + ts * 16 + l15;
      float vr[4] = {acc[es][ts][0] + b0, acc[es][ts][1] + b1,
                     acc[es][ts][2] + b2, acc[es][ts][3] + b3};
      if (proj == 0) {
        int sw = (((ecol >> 3) ^ (t & 7)) << 3) | (ecol & 7);
        uint2 u;
        u.x = (unsigned)fb(vr[0]) | ((unsigned)fb(vr[1]) << 16);
        u.y = (unsigned)fb(vr[2]) | ((unsigned)fb(vr[3]) << 16);
        *(uint2*)(kbuf + (size_t)t * 512 + sw) = u;
      } else {
        size_t tb = (size_t)(t >> 5) * 16384;
        int trel = t & 31;
#pragma unroll
        for (int i = 0; i < 4; ++i)
          vbuf[tb + (size_t)(ecol + i) * 32 + trel] = fb(vr[i]);
      }
    }
  }
}

// ---------------------------------------------------------------------------
// flash32 v2 — swapped-operand MFMA form (lane-local softmax):
//   S^T = MFMA(K, Q):  lane holds S[qrow = l15][t' = quad*4+reg (+16)]
//     -> row-max = 7 in-lane fmax + 2 shfl (was 4x 4-shfl chains)
//     -> mrow/lpart are SCALARS; P-store = 2 packed ds_write_b64
//        (was 8 scalar b16 -> the measured 3.6e7 bank-conflict source)
//   O^T = MFMA(V^T, P): lane holds O[e = quad*4+reg][qrow = l15]
//     -> V read DIRECT from L2 (tiled vbuf, contiguous 1KB/instr, no reuse
//        so LDS staging was pure overhead) — V barrier + stage removed.
// LDS = K tile 32KB + P 5KB = 37.9KB  -> 3-4 blocks/CU (was 2 at 71.7KB).
// 2 barriers/tile. Softmax in exp2 domain. Exact defer-rescale kept.
// ---------------------------------------------------------------------------
__global__ __launch_bounds__(256, 3) void flash32_kernel(
    const void* __restrict__ x, const void* __restrict__ gsc,
    const void* __restrict__ gbi, const float* __restrict__ stats,
    const void* __restrict__ w_in, const void* __restrict__ b_in,
    const unsigned short* __restrict__ kvbase,
    const void* __restrict__ w_out, const void* __restrict__ b_out,
    void* __restrict__ out, int nn0, int conc) {
  const bool f32 = detect_f32(w_in);
  int nn, t0, slot;
  if (conc) {
    int xcd = blockIdx.x & 7;
    nn = xcd >> 1;
    slot = nn;
    t0 = ((((xcd & 1) << 6) | (blockIdx.x >> 3))) << 5;
  } else {
    nn = nn0; slot = 0; t0 = blockIdx.x << 5;
  }
  const unsigned short* kbuf = kvbase + (size_t)slot * 4194304;
  const unsigned short* vbuf = kbuf + 2097152;

  __shared__ __align__(16) short lds[18944];  // 37,888 B
  short* KT = lds;                      // K tile [32][512] (swizzled granules)
  const int tid = threadIdx.x;
  const int wave = tid >> 6, lane = tid & 63, l15 = lane & 15, quad = lane >> 4;
  short* Pl = lds + 16384 + wave * 640;  // per-wave P [16 qrow][40] (t' cols)
  const int rh = wave & 1;   // row half: q-rows rh*16..+16
  const int ch = wave >> 1;  // col half: O-cols ch*256..+256

  // ================= Q phase: two 16-row passes (LDS-slim) =================
  // xnq and Qs both [16][520] inside the K/P region (K-loop not started).
  short* xnq = lds;          // 8320 shorts
  short* Qs = lds + 8320;    // 8320 shorts
  bf16x8 q[16];              // wave's 16 q-rows x 512 c, B-frag layout
  for (int h = 0; h < 2; ++h) {
    stage_xn16(xnq, x, gsc, gbi, stats, nn, t0 + h * 16, f32);
    __syncthreads();
    f32x4 qacc[8];
#pragma unroll
    for (int i = 0; i < 8; ++i) qacc[i] = {0.f, 0.f, 0.f, 0.f};
    for (int kc = 0; kc < 16; ++kc) {
      bf16x8 bx0 = frag_ld(xnq + l15 * 520 + kc * 32 + quad * 8);
#pragma unroll
      for (int es = 0; es < 8; ++es) {
        bf16x8 a = wfrag(w_in, (size_t)(wave * 128 + es * 16 + l15) * 512 + kc * 32 + quad * 8, f32);
        qacc[es] = MFMA(a, bx0, qacc[es]);
      }
    }
    // D[m=e][n=t]: col=l15=t, row=quad*4+reg=e. Qs[t][e] = (acc+b)*scale.
#pragma unroll
    for (int es = 0; es < 8; ++es) {
      int e0 = wave * 128 + es * 16 + quad * 4;
      float b0 = ld(b_in, e0, f32), b1 = ld(b_in, e0 + 1, f32);
      float b2 = ld(b_in, e0 + 2, f32), b3 = ld(b_in, e0 + 3, f32);
      uint2 u;
      u.x = (unsigned)fb((qacc[es][0] + b0) * ATTN_SCALE_L2) |
            ((unsigned)fb((qacc[es][1] + b1) * ATTN_SCALE_L2) << 16);
      u.y = (unsigned)fb((qacc[es][2] + b2) * ATTN_SCALE_L2) |
            ((unsigned)fb((qacc[es][3] + b3) * ATTN_SCALE_L2) << 16);
      *(uint2*)(Qs + l15 * 520 + e0) = u;
    }
    __syncthreads();
    if (rh == h) {  // B-frag: B[n=qrow=l15][k=c]
#pragma unroll
      for (int kc = 0; kc < 16; ++kc)
        q[kc] = frag_ld(Qs + l15 * 520 + kc * 32 + quad * 8);
    }
    __syncthreads();
  }

// per wave: 8 x 1KB global_load_lds, linear copy of its K quarter
#define STAGE_K(tk)                                                           \
  {                                                                           \
    const short* s_ = (const short*)kbuf + (size_t)(tk)*16384 + wave * 4096 + \
                      lane * 8;                                               \
    short* d_ = KT + wave * 4096;                                             \
    _Pragma("unroll") for (int i_ = 0; i_ < 8; ++i_)                          \
        gl_lds16(s_ + i_ * 512, d_ + i_ * 512);                               \
  }

  f32x4 o[16];
#pragma unroll
  for (int oc = 0; oc < 16; ++oc) o[oc] = {0.f, 0.f, 0.f, 0.f};
  float mrow = -3.0e38f, lpart = 0.f;

  STAGE_K(0);

  for (int tk = 0; tk < 128; ++tk) {
    WAITV(0);  // own K quarter landed
    BAR();     // all quarters landed

    // ---- S^T = K(32x512) @ Q^T: D[m=t'][n=qrow=l15] ----
    f32x4 s0 = {0.f, 0.f, 0.f, 0.f}, s1 = {0.f, 0.f, 0.f, 0.f};
#pragma unroll
    for (int kc = 0; kc < 16; ++kc) {
      int g = ((kc * 4 + quad) ^ (l15 & 7)) * 8;  // inverse of kbuf swizzle
      bf16x8 kb0 = frag_ld(KT + l15 * 512 + g);          // rows t' = l15
      bf16x8 kb1 = frag_ld(KT + (16 + l15) * 512 + g);   // rows t' = 16+l15
      s0 = MFMA(kb0, q[kc], s0);
      s1 = MFMA(kb1, q[kc], s1);
    }
    BAR();                           // all waves done reading K(tk)
    if (tk < 127) STAGE_K(tk + 1);   // flies under softmax + PV

    // ---- lane-local softmax (qrow = l15): in-lane max + 2 shfl ----
    float vmax = fmaxf(fmaxf(fmaxf(s0[0], s0[1]), fmaxf(s0[2], s0[3])),
                       fmaxf(fmaxf(s1[0], s1[1]), fmaxf(s1[2], s1[3])));
    vmax = fmaxf(vmax, __shfl_xor(vmax, 16));
    vmax = fmaxf(vmax, __shfl_xor(vmax, 32));
    if (__any(vmax > mrow)) {  // exact defer-rescale
      float mnew = fmaxf(mrow, vmax);
      float sc = exp2f(mrow - mnew);
      mrow = mnew;
      lpart *= sc;
#pragma unroll
      for (int oc = 0; oc < 16; ++oc) o[oc] *= sc;
    }
    float p0 = exp2f(s0[0] - mrow), p1 = exp2f(s0[1] - mrow);
    float p2 = exp2f(s0[2] - mrow), p3 = exp2f(s0[3] - mrow);
    float p4 = exp2f(s1[0] - mrow), p5 = exp2f(s1[1] - mrow);
    float p6 = exp2f(s1[2] - mrow), p7 = exp2f(s1[3] - mrow);
    lpart += ((p0 + p1) + (p2 + p3)) + ((p4 + p5) + (p6 + p7));
    uint2 u0, u1;
    u0.x = (unsigned)fb(p0) | ((unsigned)fb(p1) << 16);
    u0.y = (unsigned)fb(p2) | ((unsigned)fb(p3) << 16);
    u1.x = (unsigned)fb(p4) | ((unsigned)fb(p5) << 16);
    u1.y = (unsigned)fb(p6) | ((unsigned)fb(p7) << 16);
    *(uint2*)(Pl + l15 * 40 + quad * 4) = u0;        // t' = quad*4..+4
    *(uint2*)(Pl + l15 * 40 + 16 + quad * 4) = u1;   // t' = 16+quad*4..+4
    // B-frag: B[n=qrow=l15][k=t'=quad*8+j]  (same-wave DS, in-order)
    bf16x8 pa = frag_ld(Pl + l15 * 40 + quad * 8);

    // ---- O^T += V^T @ P: A[m=e=l15][k=t'] direct from L2 (no LDS) ----
    {
      const short* vsrc = (const short*)vbuf + (size_t)tk * 16384 +
                          ch * 8192 + quad * 8;
#pragma unroll
      for (int oc = 0; oc < 16; ++oc) {
        bf16x8 vb = frag_ld(vsrc + (oc * 16 + l15) * 32);
        o[oc] = MFMA(vb, pa, o[oc]);
      }
    }
  }

  // ---- final l reduce over quads, normalize ----
  lpart += __shfl_xor(lpart, 16);
  lpart += __shfl_xor(lpart, 32);
  float inv = 1.0f / lpart;

  __syncthreads();  // K/P regions dead; safe to overwrite with O park
  // lane holds O[e = ch*256+oc*16+quad*4+r][qrow = l15] -> park Opark[qrow][e]
#pragma unroll
  for (int oc = 0; oc < 16; ++oc) {
    uint2 u;
    u.x = (unsigned)fb(o[oc][0] * inv) | ((unsigned)fb(o[oc][1] * inv) << 16);
    u.y = (unsigned)fb(o[oc][2] * inv) | ((unsigned)fb(o[oc][3] * inv) << 16);
    *(uint2*)(lds + (rh * 16 + l15) * 520 + ch * 256 + oc * 16 + quad * 4) = u;
  }
  __syncthreads();

  // ---- out-projection: D[m=cc][n=t] = w_out @ O^T, + bias + residual ----
  f32x4 oa[8][2];
#pragma unroll
  for (int i = 0; i < 8; ++i) {
    oa[i][0] = {0.f, 0.f, 0.f, 0.f};
    oa[i][1] = {0.f, 0.f, 0.f, 0.f};
  }
  for (int kc = 0; kc < 16; ++kc) {
    bf16x8 ob0 = frag_ld(lds + l15 * 520 + kc * 32 + quad * 8);
    bf16x8 ob1 = frag_ld(lds + (16 + l15) * 520 + kc * 32 + quad * 8);
#pragma unroll
    for (int es = 0; es < 8; ++es) {
      bf16x8 a = wfrag(w_out, (size_t)(wave * 128 + es * 16 + l15) * 512 + kc * 32 + quad * 8, f32);
      oa[es][0] = MFMA(a, ob0, oa[es][0]);
      oa[es][1] = MFMA(a, ob1, oa[es][1]);
    }
  }
#pragma unroll
  for (int es = 0; es < 8; ++es) {
    int cc = wave * 128 + es * 16 + quad * 4;
    float b0 = ld(b_out, cc, f32), b1 = ld(b_out, cc + 1, f32);
    float b2 = ld(b_out, cc + 2, f32), b3 = ld(b_out, cc + 3, f32);
#pragma unroll
    for (int ts = 0; ts < 2; ++ts) {
      int t = t0 + ts * 16 + l15;
      float vr[4] = {oa[es][ts][0] + b0, oa[es][ts][1] + b1,
                     oa[es][ts][2] + b2, oa[es][ts][3] + b3};
#pragma unroll
      for (int r = 0; r < 4; ++r) {
        size_t oidx = ((size_t)(nn * C + cc + r) << 12) + t;
        float v = vr[r] + ld(x, oidx, f32);
        if (f32)
          ((float*)out)[oidx] = v;
        else
          ((unsigned short*)out)[oidx] = fb(v);
      }
    }
  }
}

// ---------------------------------------------------------------------------
extern "C" void kernel_launch(void* const* d_in, const int* in_sizes, int n_in,
                              void* d_out, int out_size, void* d_ws, size_t ws_size,
                              hipStream_t stream) {
  const void* x = d_in[0];
  const void* gn_scale = d_in[1];
  const void* gn_bias = d_in[2];
  const void* w_in = d_in[3];
  const void* b_in = d_in[4];
  const void* w_out = d_in[5];
  const void* b_out = d_in[6];
  (void)in_sizes; (void)n_in; (void)out_size;

  // ws: [stats 1KB | per-batch slot 8MB: K swizzled [t][512] + V tiled]
  float* stats = (float*)d_ws;
  unsigned short* kv0 = (unsigned short*)((char*)d_ws + 1024);
  const size_t need4 = 1024 + (size_t)4 * 4194304 * 2;

  gn_stats_kernel<<<NBATCH * GROUPS, 256, 0, stream>>>(x, w_in, stats);

  if (ws_size >= need4) {
    kv_gemm_kernel<<<dim3(4, 128, 4), 256, 0, stream>>>(
        x, gn_scale, gn_bias, stats, w_in, b_in, kv0, 0);
    flash32_kernel<<<dim3(512), 256, 0, stream>>>(
        x, gn_scale, gn_bias, stats, w_in, b_in, kv0, w_out, b_out, d_out, 0, 1);
  } else {
    for (int nn = 0; nn < NBATCH; ++nn) {
      kv_gemm_kernel<<<dim3(4, 128, 1), 256, 0, stream>>>(
          x, gn_scale, gn_bias, stats, w_in, b_in, kv0, nn);
      flash32_kernel<<<dim3(128), 256, 0, stream>>>(
          x, gn_scale, gn_bias, stats, w_in, b_in, kv0, w_out, b_out, d_out, nn, 0);
    }
  }
}

// Round 5
// 758.521 us; speedup vs baseline: 1.8825x; 1.8825x over previous
//
#include <hip/hip_runtime.h>
#include <hip/hip_bf16.h>

// n=4, c=512, h=w=64. Runtime dtype via detect_f32 (R3-proven).
#define NBATCH 4
#define C 512
#define HW 4096
#define GROUPS 32
#define EPSV 1e-5f
// attention scale folded with 1/ln2 (softmax in exp2 domain, R4-proven):
// 1/sqrt(512) * log2(e)
#define ATTN_SCALE_L2 0.0637587085f

typedef short bf16x8 __attribute__((ext_vector_type(8)));  // 8 bf16 = 4 VGPR
typedef float f32x4 __attribute__((ext_vector_type(4)));

__device__ __forceinline__ float bf(unsigned short u) {
  return __uint_as_float(((unsigned)u) << 16);
}
__device__ __forceinline__ unsigned short fb(float v) {
  __hip_bfloat16 h = __float2bfloat16(v);
  return *(unsigned short*)&h;
}
__device__ __forceinline__ bf16x8 frag_ld(const short* p) {
  return *(const bf16x8*)p;  // 16B-aligned by construction
}
#define MFMA(a, b, c) __builtin_amdgcn_mfma_f32_16x16x32_bf16((a), (b), (c), 0, 0, 0)

#define SCHED_FENCE() __builtin_amdgcn_sched_barrier(0)
// raw barrier (NO vmcnt drain) + compiler/scheduler fences (rule #18 / m152)
#define BAR()                                   \
  do {                                          \
    asm volatile("" ::: "memory");              \
    SCHED_FENCE();                              \
    __builtin_amdgcn_s_barrier();               \
    SCHED_FENCE();                              \
    asm volatile("" ::: "memory");              \
  } while (0)
#define WAITV(N)                                                  \
  do {                                                            \
    asm volatile("s_waitcnt vmcnt(" #N ")" ::: "memory");         \
    SCHED_FENCE();                                                \
  } while (0)

// async global->LDS, 16B per lane; LDS dest is wave-uniform base + lane*16
__device__ __forceinline__ void gl_lds16(const short* g, short* l) {
  __builtin_amdgcn_global_load_lds(
      (const __attribute__((address_space(1))) unsigned int*)g,
      (__attribute__((address_space(3))) unsigned int*)l, 16, 0, 0);
}

__device__ __forceinline__ void unpack8(uint4 w, float* f) {
  f[0] = __uint_as_float(w.x << 16);
  f[1] = __uint_as_float(w.x & 0xFFFF0000u);
  f[2] = __uint_as_float(w.y << 16);
  f[3] = __uint_as_float(w.y & 0xFFFF0000u);
  f[4] = __uint_as_float(w.z << 16);
  f[5] = __uint_as_float(w.z & 0xFFFF0000u);
  f[6] = __uint_as_float(w.w << 16);
  f[7] = __uint_as_float(w.w & 0xFFFF0000u);
}

// Runtime dtype detection (R3-proven).
__device__ __forceinline__ bool detect_f32(const void* w_in) {
  const unsigned short* u = (const unsigned short*)w_in;
  bool f32 = false;
#pragma unroll
  for (int i = 0; i < 64; ++i) {
    float v = bf(u[i]);
    if (!(fabsf(v) < 1e3f)) f32 = true;  // NaN -> true
  }
  return f32;
}
__device__ __forceinline__ float ld(const void* p, size_t i, bool f32) {
  if (f32) return ((const float*)p)[i];
  return bf(((const unsigned short*)p)[i]);
}

// MFMA A-fragment (8 contiguous k-elements) from a weight matrix, either dtype.
__device__ __forceinline__ bf16x8 wfrag(const void* w, size_t off, bool f32) {
  if (f32) {
    const float4* p = (const float4*)((const float*)w + off);
    float4 w0 = p[0], w1 = p[1];
    bf16x8 r;
    r[0] = (short)fb(w0.x); r[1] = (short)fb(w0.y);
    r[2] = (short)fb(w0.z); r[3] = (short)fb(w0.w);
    r[4] = (short)fb(w1.x); r[5] = (short)fb(w1.y);
    r[6] = (short)fb(w1.z); r[7] = (short)fb(w1.w);
    return r;
  }
  return frag_ld((const short*)w + off);
}

// Stage GN-normalized x rows [t0, t0+32) into xn[32][520] (bf16). R3-proven.
__device__ __forceinline__ void stage_xn(short* xn, const void* x,
                                         const void* gsc, const void* gbi,
                                         const float* stats, int nn, int t0,
                                         bool f32) {
  const int tid = threadIdx.x;
  const int part = tid & 3, crel = tid >> 2;
  for (int c0 = 0; c0 < 512; c0 += 64) {
    int c = c0 + crel;
    float rr = stats[128 + nn * GROUPS + (c >> 4)];
    float mu = stats[nn * GROUPS + (c >> 4)];
    float scl = ld(gsc, c, f32) * rr;
    float sft = ld(gbi, c, f32) - mu * scl;
    float f[8];
    if (f32) {
      const float4* p = (const float4*)((const float*)x +
                                        ((size_t)(nn * C + c) << 12) + t0 + part * 8);
      float4 r0 = p[0], r1 = p[1];
      f[0] = r0.x; f[1] = r0.y; f[2] = r0.z; f[3] = r0.w;
      f[4] = r1.x; f[5] = r1.y; f[6] = r1.z; f[7] = r1.w;
    } else {
      uint4 raw = *(const uint4*)((const unsigned short*)x +
                                  ((size_t)(nn * C + c) << 12) + t0 + part * 8);
      unpack8(raw, f);
    }
#pragma unroll
    for (int j = 0; j < 8; ++j)
      xn[(part * 8 + j) * 520 + c] = (short)fb(f[j] * scl + sft);
  }
}

// ---------------------------------------------------------------------------
// GroupNorm stats — R3-proven verbatim.
// ---------------------------------------------------------------------------
__global__ __launch_bounds__(256) void gn_stats_kernel(
    const void* __restrict__ x, const void* __restrict__ w_in,
    float* __restrict__ stats) {
  const bool f32 = detect_f32(w_in);
  const int b = blockIdx.x;
  const size_t base = (size_t)b << 16;
  float s = 0.f, ss = 0.f;
  for (int i = threadIdx.x; i < 65536; i += 256) {
    float v = ld(x, base + i, f32);
    s += v;
    ss += v * v;
  }
  __shared__ float rs[256], rq[256];
  rs[threadIdx.x] = s;
  rq[threadIdx.x] = ss;
  __syncthreads();
  for (int off = 128; off > 0; off >>= 1) {
    if (threadIdx.x < off) {
      rs[threadIdx.x] += rs[threadIdx.x + off];
      rq[threadIdx.x] += rq[threadIdx.x + off];
    }
    __syncthreads();
  }
  if (threadIdx.x == 0) {
    float m = rs[0] * (1.0f / 65536.0f);
    float var = rq[0] * (1.0f / 65536.0f) - m * m;
    stats[b] = m;
    stats[128 + b] = rsqrtf(var + EPSV);
  }
}

// ---------------------------------------------------------------------------
// kv_gemm — proven MFMA core. Epilogue (R3 550µs version, restored):
//   K: kbuf[t][col] PRE-SWIZZLED: granule g=e>>3 stored at g^(t&7).
//   V: vbuf tiled [tk][e][32] granule-swizzled: (e,trel) at granule
//      (trel>>3)^((e>>1)&3), offset trel&7 -> flash PV 2-way banks (free).
// ---------------------------------------------------------------------------
__global__ __launch_bounds__(256) void kv_gemm_kernel(
    const void* __restrict__ x, const void* __restrict__ gsc,
    const void* __restrict__ gbi, const float* __restrict__ stats,
    const void* __restrict__ w_in, const void* __restrict__ b_in,
    unsigned short* __restrict__ kvbase, int nn0) {
  const bool f32 = detect_f32(w_in);
  const int nn = nn0 + blockIdx.z;
  unsigned short* kbuf = kvbase + (size_t)blockIdx.z * 4194304;
  unsigned short* vbuf = kbuf + 2097152;
  __shared__ __align__(16) short xn[32 * 520];
  const int tid = threadIdx.x;
  const int wave = tid >> 6, lane = tid & 63, l15 = lane & 15, quad = lane >> 4;
  const int t0 = blockIdx.y * 32;
  const int proj = blockIdx.x >> 1;  // 0 = K, 1 = V
  const int ehalf = blockIdx.x & 1;

  stage_xn(xn, x, gsc, gbi, stats, nn, t0, f32);
  __syncthreads();

  const int wrow = 512 + proj * 512 + ehalf * 256 + wave * 64;  // w_in row
  const int cbase = ehalf * 256 + wave * 64;                    // col in [0,512)

  f32x4 acc[4][2];
#pragma unroll
  for (int i = 0; i < 4; ++i) {
    acc[i][0] = {0.f, 0.f, 0.f, 0.f};
    acc[i][1] = {0.f, 0.f, 0.f, 0.f};
  }

  for (int kc = 0; kc < 16; ++kc) {
    bf16x8 b0f = frag_ld(xn + l15 * 520 + kc * 32 + quad * 8);
    bf16x8 b1f = frag_ld(xn + (16 + l15) * 520 + kc * 32 + quad * 8);
#pragma unroll
    for (int es = 0; es < 4; ++es) {
      bf16x8 a = wfrag(w_in, (size_t)(wrow + es * 16 + l15) * 512 + kc * 32 + quad * 8, f32);
      acc[es][0] = MFMA(a, b0f, acc[es][0]);
      acc[es][1] = MFMA(a, b1f, acc[es][1]);
    }
  }

#pragma unroll
  for (int es = 0; es < 4; ++es) {
    int bidx = wrow + es * 16 + quad * 4;
    float b0 = ld(b_in, bidx, f32), b1 = ld(b_in, bidx + 1, f32);
    float b2 = ld(b_in, bidx + 2, f32), b3 = ld(b_in, bidx + 3, f32);
    int ecol = cbase + es * 16 + quad * 4;
#pragma unroll
    for (int ts = 0; ts < 2; ++ts) {
      int t = t0 + ts * 16 + l15;
      float vr[4] = {acc[es][ts][0] + b0, acc[es][ts][1] + b1,
                     acc[es][ts][2] + b2, acc[es][ts][3] + b3};
      if (proj == 0) {
        int sw = (((ecol >> 3) ^ (t & 7)) << 3) | (ecol & 7);
        uint2 u;
        u.x = (unsigned)fb(vr[0]) | ((unsigned)fb(vr[1]) << 16);
        u.y = (unsigned)fb(vr[2]) | ((unsigned)fb(vr[3]) << 16);
        *(uint2*)(kbuf + (size_t)t * 512 + sw) = u;
      } else {
        size_t tb = (size_t)(t >> 5) * 16384;
        int trel = t & 31;
#pragma unroll
        for (int i = 0; i < 4; ++i) {
          int e = ecol + i;
          vbuf[tb + (size_t)e * 32 + ((((trel >> 3) ^ ((e >> 1) & 3)) << 3)) +
               (trel & 7)] = fb(vr[i]);
        }
      }
    }
  }
}

// ---------------------------------------------------------------------------
// flash32 R5 — R3's proven 550µs skeleton (V in LDS, 4-barrier/vmcnt(8)
// pipeline, 71.7KB LDS, 2 blocks/CU) + lane-local softmax graft (R4-proven
// numerics):
//   S^T = MFMA(K,Q): lane holds S[qrow=l15][t' in-lane] -> row-max = 7 fmax
//     + 2 shfl; mrow/lpart SCALAR; P-store = 2 packed ds_write_b64.
//   PV: O^T = MFMA(V,P) — IDENTICAL LDS addresses as R3, roles swapped.
// s_setprio(1) wraps both MFMA clusters (T5).
// ---------------------------------------------------------------------------
__global__ __launch_bounds__(256, 2) void flash32_kernel(
    const void* __restrict__ x, const void* __restrict__ gsc,
    const void* __restrict__ gbi, const float* __restrict__ stats,
    const void* __restrict__ w_in, const void* __restrict__ b_in,
    const unsigned short* __restrict__ kvbase,
    const void* __restrict__ w_out, const void* __restrict__ b_out,
    void* __restrict__ out, int nn0, int conc) {
  const bool f32 = detect_f32(w_in);
  int nn, t0, slot;
  if (conc) {
    int xcd = blockIdx.x & 7;
    nn = xcd >> 1;
    slot = nn;
    t0 = ((((xcd & 1) << 6) | (blockIdx.x >> 3))) << 5;
  } else {
    nn = nn0; slot = 0; t0 = blockIdx.x << 5;
  }
  const unsigned short* kbuf = kvbase + (size_t)slot * 4194304;
  const unsigned short* vbuf = kbuf + 2097152;

  __shared__ __align__(16) short lds[35840];  // 71680 B
  short* RA = lds;                 // xn (Q phase) -> Ktile -> O park
  short* RB = lds + 16640;         // Qs (Q phase) -> Vtile
  const int tid = threadIdx.x;
  const int wave = tid >> 6, lane = tid & 63, l15 = lane & 15, quad = lane >> 4;
  short* Pl = lds + 33280 + wave * 640;  // per-wave P [16 qrow][40 t']
  const int rh = wave & 1;   // row half: q-rows rh*16..+16
  const int ch = wave >> 1;  // col half: O-cols ch*256..+256

  // ================= Q phase (R3-proven, scale const swapped) =============
  bf16x8 q[16];  // wave's 16 q-rows x 512 c, B-frag layout (n=qrow, k=c)
  stage_xn(RA, x, gsc, gbi, stats, nn, t0, f32);
  __syncthreads();
  {
    f32x4 qacc[8][2];
#pragma unroll
    for (int i = 0; i < 8; ++i) {
      qacc[i][0] = {0.f, 0.f, 0.f, 0.f};
      qacc[i][1] = {0.f, 0.f, 0.f, 0.f};
    }
    for (int kc = 0; kc < 16; ++kc) {
      bf16x8 bx0 = frag_ld(RA + l15 * 520 + kc * 32 + quad * 8);
      bf16x8 bx1 = frag_ld(RA + (16 + l15) * 520 + kc * 32 + quad * 8);
#pragma unroll
      for (int es = 0; es < 8; ++es) {
        bf16x8 a = wfrag(w_in, (size_t)(wave * 128 + es * 16 + l15) * 512 + kc * 32 + quad * 8, f32);
        qacc[es][0] = MFMA(a, bx0, qacc[es][0]);
        qacc[es][1] = MFMA(a, bx1, qacc[es][1]);
      }
    }
    // D[m=e][n=t] -> Qs[t][e] = (acc + b_in[e]) * ATTN_SCALE_L2 (bf16)
#pragma unroll
    for (int es = 0; es < 8; ++es) {
      int e0 = wave * 128 + es * 16 + quad * 4;
      float b0 = ld(b_in, e0, f32), b1 = ld(b_in, e0 + 1, f32);
      float b2 = ld(b_in, e0 + 2, f32), b3 = ld(b_in, e0 + 3, f32);
#pragma unroll
      for (int ts = 0; ts < 2; ++ts) {
        int t = ts * 16 + l15;
        uint2 u;
        u.x = (unsigned)fb((qacc[es][ts][0] + b0) * ATTN_SCALE_L2) |
              ((unsigned)fb((qacc[es][ts][1] + b1) * ATTN_SCALE_L2) << 16);
        u.y = (unsigned)fb((qacc[es][ts][2] + b2) * ATTN_SCALE_L2) |
              ((unsigned)fb((qacc[es][ts][3] + b3) * ATTN_SCALE_L2) << 16);
        *(uint2*)(RB + t * 520 + e0) = u;
      }
    }
    __syncthreads();
#pragma unroll
    for (int kc = 0; kc < 16; ++kc)
      q[kc] = frag_ld(RB + (rh * 16 + l15) * 520 + kc * 32 + quad * 8);
    __syncthreads();
  }

// ================= K/V tile staging macros (R3-proven) =================
#define STAGE_K(tk)                                                           \
  {                                                                           \
    const short* s_ = (const short*)kbuf + (size_t)(tk)*16384 + wave * 4096 + \
                      lane * 8;                                               \
    short* d_ = RA + wave * 4096;                                             \
    _Pragma("unroll") for (int i_ = 0; i_ < 8; ++i_)                          \
        gl_lds16(s_ + i_ * 512, d_ + i_ * 512);                               \
  }
#define STAGE_V(tk)                                                           \
  {                                                                           \
    const short* s_ = (const short*)vbuf + (size_t)(tk)*16384 + wave * 4096 + \
                      lane * 8;                                               \
    short* d_ = RB + wave * 4096;                                             \
    _Pragma("unroll") for (int i_ = 0; i_ < 8; ++i_)                          \
        gl_lds16(s_ + i_ * 512, d_ + i_ * 512);                               \
  }

  f32x4 o[16];
#pragma unroll
  for (int oc = 0; oc < 16; ++oc) o[oc] = {0.f, 0.f, 0.f, 0.f};
  float mrow = -3.0e38f, lpart = 0.f;

  STAGE_K(0);
  STAGE_V(0);

  for (int tk = 0; tk < 128; ++tk) {
    WAITV(8);  // K(tk) landed (V(tk) may still fly)
    BAR();

    // ---- S^T = K(32x512) @ Q^T: D[m=t'][n=qrow=l15] ----
    f32x4 s0 = {0.f, 0.f, 0.f, 0.f}, s1 = {0.f, 0.f, 0.f, 0.f};
    __builtin_amdgcn_s_setprio(1);
#pragma unroll
    for (int kc = 0; kc < 16; ++kc) {
      int g = ((kc * 4 + quad) ^ (l15 & 7)) * 8;  // inverse of kbuf swizzle
      bf16x8 kb0 = frag_ld(RA + l15 * 512 + g);          // A rows t' = l15
      bf16x8 kb1 = frag_ld(RA + (16 + l15) * 512 + g);   // A rows t' = 16+l15
      s0 = MFMA(kb0, q[kc], s0);
      s1 = MFMA(kb1, q[kc], s1);
    }
    __builtin_amdgcn_s_setprio(0);
    BAR();                           // all waves done reading K(tk)
    if (tk < 127) STAGE_K(tk + 1);   // flies under softmax + PV

    // ---- lane-local softmax (qrow = l15): 7 in-lane fmax + 2 shfl ----
    float vmax = fmaxf(fmaxf(fmaxf(s0[0], s0[1]), fmaxf(s0[2], s0[3])),
                       fmaxf(fmaxf(s1[0], s1[1]), fmaxf(s1[2], s1[3])));
    vmax = fmaxf(vmax, __shfl_xor(vmax, 16));
    vmax = fmaxf(vmax, __shfl_xor(vmax, 32));
    if (__any(vmax > mrow)) {  // exact defer-rescale
      float mnew = fmaxf(mrow, vmax);
      float sc = exp2f(mrow - mnew);
      mrow = mnew;
      lpart *= sc;
#pragma unroll
      for (int oc = 0; oc < 16; ++oc) o[oc] *= sc;
    }
    float p0 = exp2f(s0[0] - mrow), p1 = exp2f(s0[1] - mrow);
    float p2 = exp2f(s0[2] - mrow), p3 = exp2f(s0[3] - mrow);
    float p4 = exp2f(s1[0] - mrow), p5 = exp2f(s1[1] - mrow);
    float p6 = exp2f(s1[2] - mrow), p7 = exp2f(s1[3] - mrow);
    lpart += ((p0 + p1) + (p2 + p3)) + ((p4 + p5) + (p6 + p7));
    uint2 u0, u1;
    u0.x = (unsigned)fb(p0) | ((unsigned)fb(p1) << 16);
    u0.y = (unsigned)fb(p2) | ((unsigned)fb(p3) << 16);
    u1.x = (unsigned)fb(p4) | ((unsigned)fb(p5) << 16);
    u1.y = (unsigned)fb(p6) | ((unsigned)fb(p7) << 16);
    *(uint2*)(Pl + l15 * 40 + quad * 4) = u0;        // t' = quad*4..+4
    *(uint2*)(Pl + l15 * 40 + 16 + quad * 4) = u1;   // t' = 16+quad*4..+4
    // B-frag: B[n=qrow=l15][k=t'=quad*8+j]  (same-wave DS, in-order)
    bf16x8 pa = frag_ld(Pl + l15 * 40 + quad * 8);

    if (tk == 127) { WAITV(0); } else { WAITV(8); }  // V(tk) landed
    BAR();

    // ---- O^T += V^T @ P: D[m=e][n=qrow], V from LDS (R3 addresses) ----
    __builtin_amdgcn_s_setprio(1);
#pragma unroll
    for (int oc = 0; oc < 16; ++oc) {
      int e = ch * 256 + oc * 16 + l15;
      bf16x8 vb = frag_ld(RB + e * 32 + ((quad ^ ((l15 >> 1) & 3)) << 3));
      o[oc] = MFMA(vb, pa, o[oc]);
    }
    __builtin_amdgcn_s_setprio(0);
    BAR();  // all waves done reading Vtile
    if (tk < 127) STAGE_V(tk + 1);  // flies under next S
  }

  // ---- final l reduce over quads (2 shfl), normalize ----
  lpart += __shfl_xor(lpart, 16);
  lpart += __shfl_xor(lpart, 32);
  float inv = 1.0f / lpart;

  __syncthreads();  // K/P regions dead; safe to overwrite with O park
  // lane holds O[e = ch*256+oc*16+quad*4+r][qrow = l15] -> Opark[qrow][e]
#pragma unroll
  for (int oc = 0; oc < 16; ++oc) {
    uint2 u;
    u.x = (unsigned)fb(o[oc][0] * inv) | ((unsigned)fb(o[oc][1] * inv) << 16);
    u.y = (unsigned)fb(o[oc][2] * inv) | ((unsigned)fb(o[oc][3] * inv) << 16);
    *(uint2*)(lds + (rh * 16 + l15) * 520 + ch * 256 + oc * 16 + quad * 4) = u;
  }
  __syncthreads();

  // ---- out-projection: D[m=cc][n=t] = w_out @ O^T, + bias + residual ----
  f32x4 oa[8][2];
#pragma unroll
  for (int i = 0; i < 8; ++i) {
    oa[i][0] = {0.f, 0.f, 0.f, 0.f};
    oa[i][1] = {0.f, 0.f, 0.f, 0.f};
  }
  for (int kc = 0; kc < 16; ++kc) {
    bf16x8 ob0 = frag_ld(lds + l15 * 520 + kc * 32 + quad * 8);
    bf16x8 ob1 = frag_ld(lds + (16 + l15) * 520 + kc * 32 + quad * 8);
#pragma unroll
    for (int es = 0; es < 8; ++es) {
      bf16x8 a = wfrag(w_out, (size_t)(wave * 128 + es * 16 + l15) * 512 + kc * 32 + quad * 8, f32);
      oa[es][0] = MFMA(a, ob0, oa[es][0]);
      oa[es][1] = MFMA(a, ob1, oa[es][1]);
    }
  }
#pragma unroll
  for (int es = 0; es < 8; ++es) {
    int cc = wave * 128 + es * 16 + quad * 4;
    float b0 = ld(b_out, cc, f32), b1 = ld(b_out, cc + 1, f32);
    float b2 = ld(b_out, cc + 2, f32), b3 = ld(b_out, cc + 3, f32);
#pragma unroll
    for (int ts = 0; ts < 2; ++ts) {
      int t = t0 + ts * 16 + l15;
      float vr[4] = {oa[es][ts][0] + b0, oa[es][ts][1] + b1,
                     oa[es][ts][2] + b2, oa[es][ts][3] + b3};
#pragma unroll
      for (int r = 0; r < 4; ++r) {
        size_t oidx = ((size_t)(nn * C + cc + r) << 12) + t;
        float v = vr[r] + ld(x, oidx, f32);
        if (f32)
          ((float*)out)[oidx] = v;
        else
          ((unsigned short*)out)[oidx] = fb(v);
      }
    }
  }
}

// ---------------------------------------------------------------------------
extern "C" void kernel_launch(void* const* d_in, const int* in_sizes, int n_in,
                              void* d_out, int out_size, void* d_ws, size_t ws_size,
                              hipStream_t stream) {
  const void* x = d_in[0];
  const void* gn_scale = d_in[1];
  const void* gn_bias = d_in[2];
  const void* w_in = d_in[3];
  const void* b_in = d_in[4];
  const void* w_out = d_in[5];
  const void* b_out = d_in[6];
  (void)in_sizes; (void)n_in; (void)out_size;

  // ws: [stats 1KB | per-batch slot 8MB: K swizzled [t][512] + V tiled/swz]
  float* stats = (float*)d_ws;
  unsigned short* kv0 = (unsigned short*)((char*)d_ws + 1024);
  const size_t need4 = 1024 + (size_t)4 * 4194304 * 2;

  gn_stats_kernel<<<NBATCH * GROUPS, 256, 0, stream>>>(x, w_in, stats);

  if (ws_size >= need4) {
    kv_gemm_kernel<<<dim3(4, 128, 4), 256, 0, stream>>>(
        x, gn_scale, gn_bias, stats, w_in, b_in, kv0, 0);
    flash32_kernel<<<dim3(512), 256, 0, stream>>>(
        x, gn_scale, gn_bias, stats, w_in, b_in, kv0, w_out, b_out, d_out, 0, 1);
  } else {
    for (int nn = 0; nn < NBATCH; ++nn) {
      kv_gemm_kernel<<<dim3(4, 128, 1), 256, 0, stream>>>(
          x, gn_scale, gn_bias, stats, w_in, b_in, kv0, nn);
      flash32_kernel<<<dim3(128), 256, 0, stream>>>(
          x, gn_scale, gn_bias, stats, w_in, b_in, kv0, w_out, b_out, d_out, nn, 0);
    }
  }
}